// Round 9
// baseline (651.687 us; speedup 1.0000x reference)
//
#include <hip/hip_runtime.h>

#define NB 2048
#define NT 128

typedef float v2f __attribute__((ext_vector_type(2)));

static __device__ __forceinline__ v2f pkfma(v2f a, v2f b, v2f c) {
#if __has_builtin(__builtin_elementwise_fma)
    return __builtin_elementwise_fma(a, b, c);
#else
    v2f r; r.x = fmaf(a.x, b.x, c.x); r.y = fmaf(a.y, b.y, c.y); return r;
#endif
}
static __device__ __forceinline__ v2f mkv2(float x, float y) { v2f r; r.x = x; r.y = y; return r; }

// p + p[lane^32], computed on the VALU pipe (no ds_bpermute / lgkm wait).
// Symmetric x+y form -> independent of the builtin's return-pair order.
static __device__ __forceinline__ float sum32(float p) {
#if __has_builtin(__builtin_amdgcn_permlane32_swap)
    typedef unsigned uv2 __attribute__((ext_vector_type(2)));
    uv2 r = __builtin_amdgcn_permlane32_swap(__float_as_uint(p), __float_as_uint(p), false, false);
    return __uint_as_float(r.x) + __uint_as_float(r.y);
#else
    return p + __shfl_xor(p, 32, 64);
#endif
}

// ---------------------------------------------------------------------------
// Kernel 1: action-latent MLP  (B*T, 8) -> relu(64) -> (B*T, 16), into d_ws
// ---------------------------------------------------------------------------
__global__ __launch_bounds__(256, 4) void acl_kernel(
    const float* __restrict__ acs, const float* __restrict__ acW0,
    const float* __restrict__ acb0, const float* __restrict__ acW1,
    const float* __restrict__ acb1, float* __restrict__ aclout)
{
    __shared__ float sW0[64 * 8];
    __shared__ float sW1[16 * 64];
    __shared__ float sB0[64];
    __shared__ float sB1[16];
    const int tid = threadIdx.x;
    for (int i = tid; i < 64 * 8; i += 256) sW0[i] = acW0[i];
    for (int i = tid; i < 16 * 64; i += 256) sW1[i] = acW1[i];
    if (tid < 64) sB0[tid] = acb0[tid];
    if (tid < 16) sB1[tid] = acb1[tid];
    __syncthreads();

    const int row = blockIdx.x * 256 + tid;
    const float4 x0 = *(const float4*)&acs[row * 8];
    const float4 x1 = *(const float4*)&acs[row * 8 + 4];

    float o[16];
    #pragma unroll
    for (int m = 0; m < 16; ++m) o[m] = sB1[m];

    #pragma unroll
    for (int jc = 0; jc < 16; ++jc) {
        float hq[4];
        #pragma unroll
        for (int u = 0; u < 4; ++u) {
            const int j = jc * 4 + u;
            const float4 wa = *(const float4*)&sW0[j * 8];
            const float4 wb = *(const float4*)&sW0[j * 8 + 4];
            float hv = sB0[j];
            hv = fmaf(x0.x, wa.x, hv); hv = fmaf(x0.y, wa.y, hv);
            hv = fmaf(x0.z, wa.z, hv); hv = fmaf(x0.w, wa.w, hv);
            hv = fmaf(x1.x, wb.x, hv); hv = fmaf(x1.y, wb.y, hv);
            hv = fmaf(x1.z, wb.z, hv); hv = fmaf(x1.w, wb.w, hv);
            hq[u] = fmaxf(hv, 0.f);
        }
        #pragma unroll
        for (int m = 0; m < 16; ++m) {
            const float4 wv = *(const float4*)&sW1[m * 64 + jc * 4];
            o[m] = fmaf(hq[0], wv.x, o[m]);
            o[m] = fmaf(hq[1], wv.y, o[m]);
            o[m] = fmaf(hq[2], wv.z, o[m]);
            o[m] = fmaf(hq[3], wv.w, o[m]);
        }
    }
    float4* op = (float4*)&aclout[row * 16];
    op[0] = make_float4(o[0],  o[1],  o[2],  o[3]);
    op[1] = make_float4(o[4],  o[5],  o[6],  o[7]);
    op[2] = make_float4(o[8],  o[9],  o[10], o[11]);
    op[3] = make_float4(o[12], o[13], o[14], o[15]);
}

// ---------------------------------------------------------------------------
// Kernel 2 v10: v7 gproj structure + ystar recurrence (v8-verified algebra)
// + all cross-lane combines moved off the DS pipe via permlane32_swap.
//   per substep: 6 LDS round trips (6 gproj), 0 ds_bpermute; a1 needs no LDS;
//   y materialized once per interval (1 amortized round trip).
//   gproj combine: g = own + partner(par) rewritten order-independently as
//   d + 0.5*(sum32(s) - sum32(d)),  s = own+par, d = own-par.
// ---------------------------------------------------------------------------
__global__ __launch_bounds__(256, 2) void ode_kernel(
    const float* __restrict__ encW0, const float* __restrict__ encb0,
    const float* __restrict__ encW1, const float* __restrict__ encb1,
    const float* __restrict__ dynW0, const float* __restrict__ dynb0,
    const float* __restrict__ dynW1, const float* __restrict__ dynb1,
    const float* __restrict__ ob,    const float* __restrict__ times,
    const float* __restrict__ aclws, float* __restrict__ yio)
{
    __shared__ float sEncW0T[64 * 64];   // [k][j]
    __shared__ float sEncW1T[64 * 32];   // [j][m]
    __shared__ float sW0s[64 * 32];      // W0y rows: [j][m]
    __shared__ float sW1T[64 * 32];      // W1 cols:  [j'][m]
    __shared__ float sM[64 * 64];        // M[j][j'] = sum_m W0y[j][m] W1[m][j']
    __shared__ float sEncB0[64], sEncB1[32], sB1d[32];
    __shared__ float xbuf[4][64];
    __shared__ float hbuf[4][64];
    __shared__ float tbuf[4][NT];

    const int tid = threadIdx.x;
    for (int i = tid; i < 64 * 64; i += 256) { int r = i >> 6, c = i & 63; sEncW0T[c * 64 + r] = encW0[i]; }
    for (int i = tid; i < 32 * 64; i += 256) { int r = i >> 6, c = i & 63; sEncW1T[c * 32 + r] = encW1[i]; }
    for (int i = tid; i < 64 * 32; i += 256) { int j = i >> 5, mm = i & 31; sW0s[i] = dynW0[j * 48 + mm]; }
    for (int i = tid; i < 64 * 32; i += 256) { int c = i >> 5, mm = i & 31; sW1T[i] = dynW1[mm * 64 + c]; }
    if (tid < 64) { sEncB0[tid] = encb0[tid]; }
    if (tid < 32) { sEncB1[tid] = encb1[tid]; sB1d[tid] = dynb1[tid]; }
    __syncthreads();

    // ---- compute sM cooperatively: thread t -> row j = t>>2, 16 cols
    {
        const int j  = tid >> 2;
        const int cg = (tid & 3) * 16;
        float4 wr[8];
        #pragma unroll
        for (int q = 0; q < 8; ++q) wr[q] = *(const float4*)&sW0s[j * 32 + q * 4];
        #pragma unroll 2
        for (int k = 0; k < 16; ++k) {
            const int c = cg + k;
            v2f s0 = mkv2(0.f, 0.f), s1 = mkv2(0.f, 0.f);
            #pragma unroll
            for (int q = 0; q < 8; ++q) {
                const float4 t4 = *(const float4*)&sW1T[c * 32 + q * 4];
                s0 = pkfma(mkv2(t4.x, t4.y), mkv2(wr[q].x, wr[q].y), s0);
                s1 = pkfma(mkv2(t4.z, t4.w), mkv2(wr[q].z, wr[q].w), s1);
            }
            sM[j * 64 + c] = (s0.x + s1.x) + (s0.y + s1.y);
        }
    }
    __syncthreads();

    const int w    = tid >> 6;
    const int lane = tid & 63;
    const int bu   = __builtin_amdgcn_readfirstlane(blockIdx.x * 4 + w);
    const int m    = lane & 31;
    const int H    = lane & 32;          // which half of j'-space this lane reads

    float* __restrict__ xb = xbuf[w];
    float* __restrict__ hb = hbuf[w];

    // per-lane weights: M half-rows (own row lane, partner-source row lane^32),
    // W1 half-row (y-update), acl columns of W0 row lane
    float Maf[32], Mbf[32];
    #pragma unroll
    for (int q = 0; q < 8; ++q) *(float4*)&Maf[q * 4] = *(const float4*)&sM[lane * 64 + H + q * 4];
    #pragma unroll
    for (int q = 0; q < 8; ++q) *(float4*)&Mbf[q * 4] = *(const float4*)&sM[(lane ^ 32) * 64 + H + q * 4];
    const v2f* Ma = (const v2f*)Maf;
    const v2f* Mb = (const v2f*)Mbf;
    float w1rf[32];
    #pragma unroll
    for (int q = 0; q < 8; ++q)  *(float4*)&w1rf[q * 4] = *(const float4*)&dynW1[m * 64 + H + q * 4];
    const v2f* w1r = (const v2f*)w1rf;
    float wa[16];
    #pragma unroll
    for (int q = 0; q < 4; ++q) *(float4*)&wa[q * 4] = *(const float4*)&dynW0[lane * 48 + 32 + q * 4];
    const float b0r = dynb0[lane];
    const float b1r = dynb1[m];

    // vj = W0y[lane,:] . b1
    float vj = 0.f;
    #pragma unroll
    for (int q = 0; q < 8; ++q) {
        const float4 wv = *(const float4*)&dynW0[lane * 48 + q * 4];
        vj = fmaf(wv.x, sB1d[q * 4 + 0], vj); vj = fmaf(wv.y, sB1d[q * 4 + 1], vj);
        vj = fmaf(wv.z, sB1d[q * 4 + 2], vj); vj = fmaf(wv.w, sB1d[q * 4 + 3], vj);
    }

    tbuf[w][lane]      = times[bu * NT + lane];
    tbuf[w][64 + lane] = times[bu * NT + 64 + lane];
    __builtin_amdgcn_wave_barrier();

    // g_j = M[j,:].h + vj : half-dots + order-independent permlane combine
    auto gproj = [&](float hsv) -> float {
        __builtin_amdgcn_wave_barrier();
        hb[lane] = hsv;
        __builtin_amdgcn_wave_barrier();
        float hr[32];
        #pragma unroll
        for (int q = 0; q < 8; ++q) *(float4*)&hr[q * 4] = *(const float4*)&hb[H + q * 4];
        const v2f* hp = (const v2f*)hr;
        v2f O0 = mkv2(0.f, 0.f), O1 = mkv2(0.f, 0.f);
        v2f P0 = mkv2(0.f, 0.f), P1 = mkv2(0.f, 0.f);
        #pragma unroll
        for (int q = 0; q < 16; q += 2) {
            O0 = pkfma(hp[q],     Ma[q],     O0);
            O1 = pkfma(hp[q + 1], Ma[q + 1], O1);
            P0 = pkfma(hp[q],     Mb[q],     P0);
            P1 = pkfma(hp[q + 1], Mb[q + 1], P1);
        }
        const float own = (O0.x + O1.x) + (O0.y + O1.y);
        const float par = (P0.x + P1.x) + (P0.y + P1.y);
        const float s = own + par, d = own - par;
        // own + partner(par) = d + 0.5*(sum32(s) - sum32(d))
        return fmaf(0.5f, sum32(s) - sum32(d), d) + vj;
    };

    // ---- encoder: ob(64) -> relu(64) -> y(32), y replicated in both halves
    float y;
    {
        xb[lane] = ob[bu * 64 + lane];
        __builtin_amdgcn_wave_barrier();
        float4 xv[16];
        #pragma unroll
        for (int q = 0; q < 16; ++q) xv[q] = *(const float4*)&xb[q * 4];
        float a0 = sEncB0[lane], a1 = 0.f, a2 = 0.f, a3 = 0.f;
        #pragma unroll
        for (int q = 0; q < 16; ++q) {
            a0 = fmaf(xv[q].x, sEncW0T[(q * 4 + 0) * 64 + lane], a0);
            a1 = fmaf(xv[q].y, sEncW0T[(q * 4 + 1) * 64 + lane], a1);
            a2 = fmaf(xv[q].z, sEncW0T[(q * 4 + 2) * 64 + lane], a2);
            a3 = fmaf(xv[q].w, sEncW0T[(q * 4 + 3) * 64 + lane], a3);
        }
        const float hj = fmaxf((a0 + a1) + (a2 + a3), 0.f);
        hb[lane] = hj;
        __builtin_amdgcn_wave_barrier();
        float4 hv[8];
        #pragma unroll
        for (int q = 0; q < 8; ++q) hv[q] = *(const float4*)&hb[H + q * 4];
        float c0 = 0.f, c1 = 0.f, c2 = 0.f, c3 = 0.f;
        #pragma unroll
        for (int q = 0; q < 8; ++q) {
            c0 = fmaf(hv[q].x, sEncW1T[(H + q * 4 + 0) * 32 + m], c0);
            c1 = fmaf(hv[q].y, sEncW1T[(H + q * 4 + 1) * 32 + m], c1);
            c2 = fmaf(hv[q].z, sEncW1T[(H + q * 4 + 2) * 32 + m], c2);
            c3 = fmaf(hv[q].w, sEncW1T[(H + q * 4 + 3) * 32 + m], c3);
        }
        const float part = (c0 + c1) + (c2 + c3);
        y = sum32(part) + sEncB1[m];     // symmetric combine, order-safe
    }

    // ---- init ystar = W0y[lane,:].y  (one x-broadcast round trip, once)
    float ystar = 0.f;
    {
        __builtin_amdgcn_wave_barrier();
        xb[m] = y;                        // both pair-lanes: same addr, same data
        __builtin_amdgcn_wave_barrier();
        #pragma unroll
        for (int q = 0; q < 8; ++q) {
            const float4 wv = *(const float4*)&dynW0[lane * 48 + q * 4];
            const float4 xv = *(const float4*)&xb[q * 4];
            ystar = fmaf(wv.x, xv.x, ystar); ystar = fmaf(wv.y, xv.y, ystar);
            ystar = fmaf(wv.z, xv.z, ystar); ystar = fmaf(wv.w, xv.w, ystar);
        }
    }

    // per-lane acl partial: aclPart = sum_k w0[lane][32+k] * acl[k]
    auto acl_part = [&](const float* __restrict__ ap) -> float {
        float ar[16];
        #pragma unroll
        for (int q = 0; q < 4; ++q) *(float4*)&ar[q * 4] = *(const float4*)&ap[q * 4];
        const v2f* a2 = (const v2f*)ar;
        const v2f* wq = (const v2f*)wa;
        v2f s0 = mkv2(0.f, 0.f), s1 = mkv2(0.f, 0.f);
        #pragma unroll
        for (int q = 0; q < 8; q += 2) {
            s0 = pkfma(a2[q],     wq[q],     s0);
            s1 = pkfma(a2[q + 1], wq[q + 1], s1);
        }
        const v2f s = s0 + s1;
        return s.x + s.y;
    };

    auto store_y = [&](float yv, int t) {
        if (lane < 32) yio[(size_t)(bu * NT + t) * 64 + lane] = yv;
    };

    float aclPartC = acl_part(aclws + (size_t)(bu * NT) * 16);
    store_y(y, 0);

    for (int i = 0; i < NT - 1; ++i) {
        const float t0v = tbuf[w][i];
        const float t1v = tbuf[w][i + 1];
        const float hh  = (t1v - t0v) * 0.5f;                       // /K, K=2
        const float aclPartN = acl_part(aclws + (size_t)(bu * NT + i + 1) * 16);
        float haccS = 0.f;

        #pragma unroll 1
        for (int sub = 0; sub < 2; ++sub) {
            const float tsub  = t0v + (float)sub * hh;
            // stage-6 time fl(tsub+hh): matches reference searchsorted('right')
            const bool  swap6 = (tsub + hh >= t1v);

            const float a1v = ystar + b0r + aclPartC;

            const float h1 = fmaxf(a1v, 0.f);
            const float g1 = hh * gproj(h1);
            const float h2 = fmaxf(fmaf(0.2f, g1, a1v), 0.f);
            const float g2 = hh * gproj(h2);
            const float h3 = fmaxf(fmaf(0.075f, g1, fmaf(0.225f, g2, a1v)), 0.f);
            const float g3 = hh * gproj(h3);
            const float h4 = fmaxf(
                fmaf((float)(44.0/45.0), g1,
                fmaf((float)(-56.0/15.0), g2,
                fmaf((float)(32.0/9.0), g3, a1v))), 0.f);
            const float g4 = hh * gproj(h4);
            const float h5 = fmaxf(
                fmaf((float)(19372.0/6561.0), g1,
                fmaf((float)(-25360.0/2187.0), g2,
                fmaf((float)(64448.0/6561.0), g3,
                fmaf((float)(-212.0/729.0), g4, a1v)))), 0.f);
            const float g5 = hh * gproj(h5);
            float a6v =
                fmaf((float)(9017.0/3168.0), g1,
                fmaf((float)(-355.0/33.0), g2,
                fmaf((float)(46732.0/5247.0), g3,
                fmaf((float)(49.0/176.0), g4,
                fmaf((float)(-5103.0/18656.0), g5, a1v)))));
            a6v += swap6 ? (aclPartN - aclPartC) : 0.f;
            const float h6 = fmaxf(a6v, 0.f);

            // hacc = sum_s B_s h_s  (B2 = 0)
            float ha = (float)(35.0/384.0) * h1;
            ha = fmaf((float)(500.0/1113.0),   h3, ha);
            ha = fmaf((float)(125.0/192.0),    h4, ha);
            ha = fmaf((float)(-2187.0/6784.0), h5, ha);
            ha = fmaf((float)(11.0/84.0),      h6, ha);

            // ystar advance: W0y.y_next = W0y.y + hh*(M.hacc + v)
            const float gacc = gproj(ha);
            ystar = fmaf(hh, gacc, ystar);
            haccS += ha;
        }

        // y materialization, once per interval: y += hh*(W1.haccS + 2*b1)
        {
            __builtin_amdgcn_wave_barrier();
            hb[lane] = haccS;
            __builtin_amdgcn_wave_barrier();
            float hr[32];
            #pragma unroll
            for (int q = 0; q < 8; ++q) *(float4*)&hr[q * 4] = *(const float4*)&hb[H + q * 4];
            const v2f* hp = (const v2f*)hr;
            v2f c0 = mkv2(0.f, 0.f), c1 = mkv2(0.f, 0.f);
            #pragma unroll
            for (int q = 0; q < 16; q += 2) {
                c0 = pkfma(hp[q],     w1r[q],     c0);
                c1 = pkfma(hp[q + 1], w1r[q + 1], c1);
            }
            const float part = (c0.x + c1.x) + (c0.y + c1.y);
            const float full = sum32(part);       // symmetric, order-safe
            y = fmaf(hh, full + 2.f * b1r, y);
        }
        aclPartC = aclPartN;
        store_y(y, i + 1);
    }
}

// ---------------------------------------------------------------------------
// Kernel 3: decoder, one thread per (b,t) row, IN PLACE on out. Packed fp32.
// ---------------------------------------------------------------------------
__global__ __launch_bounds__(256, 2) void dec_kernel(
    const float* __restrict__ decW0, const float* __restrict__ decb0,
    const float* __restrict__ decW1, const float* __restrict__ decb1,
    float* __restrict__ yio)
{
    __shared__ float sW0[64 * 32];   // [j][k] as stored
    __shared__ float sW1T[64 * 64];  // [j][n]
    __shared__ float sB0[64];
    __shared__ float sB1[64];
    const int tid = threadIdx.x;
    for (int i = tid; i < 64 * 32; i += 256) sW0[i] = decW0[i];
    for (int i = tid; i < 64 * 64; i += 256) { int n = i >> 6, j = i & 63; sW1T[j * 64 + n] = decW1[i]; }
    if (tid < 64) { sB0[tid] = decb0[tid]; sB1[tid] = decb1[tid]; }
    __syncthreads();

    const size_t row = (size_t)blockIdx.x * 256 + tid;
    float* rp = &yio[row * 64];

    float xr[32];
    #pragma unroll
    for (int q = 0; q < 8; ++q) *(float4*)&xr[q * 4] = *(const float4*)&rp[q * 4];

    v2f o2[32];
    #pragma unroll
    for (int n = 0; n < 32; ++n) o2[n] = mkv2(sB1[2 * n], sB1[2 * n + 1]);

    #pragma unroll 4
    for (int j = 0; j < 64; ++j) {
        v2f a0 = mkv2(sB0[j], 0.f), a1 = mkv2(0.f, 0.f);
        #pragma unroll
        for (int q = 0; q < 8; ++q) {
            const float4 wv = *(const float4*)&sW0[j * 32 + q * 4];
            a0 = pkfma(*(const v2f*)&xr[q * 4],     mkv2(wv.x, wv.y), a0);
            a1 = pkfma(*(const v2f*)&xr[q * 4 + 2], mkv2(wv.z, wv.w), a1);
        }
        const float hj = fmaxf((a0.x + a1.x) + (a0.y + a1.y), 0.f);
        const v2f h2 = mkv2(hj, hj);
        #pragma unroll
        for (int q = 0; q < 16; ++q) {
            const float4 wv = *(const float4*)&sW1T[j * 64 + q * 4];
            o2[2 * q]     = pkfma(h2, mkv2(wv.x, wv.y), o2[2 * q]);
            o2[2 * q + 1] = pkfma(h2, mkv2(wv.z, wv.w), o2[2 * q + 1]);
        }
    }

    #pragma unroll
    for (int q = 0; q < 16; ++q)
        *(float4*)&rp[q * 4] = make_float4(o2[2 * q].x, o2[2 * q].y,
                                           o2[2 * q + 1].x, o2[2 * q + 1].y);
}

extern "C" void kernel_launch(void* const* d_in, const int* in_sizes, int n_in,
                              void* d_out, int out_size, void* d_ws, size_t ws_size,
                              hipStream_t stream)
{
    const float* encW0 = (const float*)d_in[0];
    const float* encb0 = (const float*)d_in[1];
    const float* encW1 = (const float*)d_in[2];
    const float* encb1 = (const float*)d_in[3];
    const float* acW0  = (const float*)d_in[4];
    const float* acb0  = (const float*)d_in[5];
    const float* acW1  = (const float*)d_in[6];
    const float* acb1  = (const float*)d_in[7];
    const float* dynW0 = (const float*)d_in[8];
    const float* dynb0 = (const float*)d_in[9];
    const float* dynW1 = (const float*)d_in[10];
    const float* dynb1 = (const float*)d_in[11];
    const float* decW0 = (const float*)d_in[12];
    const float* decb0 = (const float*)d_in[13];
    const float* decW1 = (const float*)d_in[14];
    const float* decb1 = (const float*)d_in[15];
    const float* ob    = (const float*)d_in[16];
    const float* acs   = (const float*)d_in[17];
    const float* times = (const float*)d_in[18];
    float* out = (float*)d_out;
    float* acl = (float*)d_ws;   // NB*NT*16 floats = 16.8 MB scratch

    acl_kernel<<<(NB * NT) / 256, 256, 0, stream>>>(acs, acW0, acb0, acW1, acb1, acl);
    ode_kernel<<<NB / 4, 256, 0, stream>>>(encW0, encb0, encW1, encb1,
                                           dynW0, dynb0, dynW1, dynb1,
                                           ob, times, acl, out);
    dec_kernel<<<(NB * NT) / 256, 256, 0, stream>>>(decW0, decb0, decW1, decb1, out);
}